// Round 7
// baseline (3784.145 us; speedup 1.0000x reference)
//
#include <hip/hip_runtime.h>
#include <stdint.h>
#include <math.h>

#define B_ 64
#define S_ 512
#define I_ 128
#define H_ 2048
#define O_ 128
#define NWG 256            /* B-split: 2 independent 32-row RNN chains */
#define COLS 16
#define NTHREADS 256
#define SLAB (B_ * H_)      /* 131072 elements per h snapshot */
#define RSTR 20             /* sRed row stride in floats */
#define SENTW 0x7FC07FC0u   /* qNaN|qNaN — tanh output always has bit14=0 */
#define SENTMASK 0x40004000u

typedef __attribute__((ext_vector_type(8))) __bf16 bf16x8;
typedef __attribute__((ext_vector_type(4))) float floatx4;
typedef __attribute__((ext_vector_type(2))) float floatx2;
typedef __attribute__((ext_vector_type(4))) unsigned int uintx4;

__device__ __forceinline__ unsigned short f2bf(float f) {
    unsigned u = __float_as_uint(f);
    unsigned r = u + 0x7fffu + ((u >> 16) & 1u);   // RNE
    return (unsigned short)(r >> 16);
}
__device__ __forceinline__ float bf2f(unsigned short h) {
    return __uint_as_float(((unsigned)h) << 16);
}
// tanh(x) = 1 - 2/(e^{2x}+1); err ~1e-6 << bf16 noise.
__device__ __forceinline__ float fast_tanh(float x) {
    float e = __expf(2.0f * x);
    return 1.0f - 2.0f * __builtin_amdgcn_rcpf(e + 1.0f);
}

// VALU burn: keeps the SIMD visibly busy while VMEM RTs are in flight so
// the SMU doesn't park SCLK at the ~730 MHz floor (r15/r16 inference:
// effective clock ~0.71 GHz all session; burn(48) -> -10% wall at equal
// cycle count). Two independent FMA chains; asm volatile so not DCE'd.
__device__ __forceinline__ void burn(int n) {
    float a = 1.0f, b = 1.0f;
    const float c = 1.0000001f, d = 0.9999999f;
    for (int i = 0; i < n; ++i)
        asm volatile("v_fmac_f32 %0, %2, %2\n\tv_fmac_f32 %1, %3, %3"
                     : "+v"(a), "+v"(b) : "v"(c), "v"(d));
}

// sc0 sc1 loads (bypass L1/L2 -> MALL truth; retry-safe)
#define LDG0(dst, addr) \
    asm volatile("global_load_dwordx4 %0, %1, off sc0 sc1" \
                 : "=v"(dst) : "v"(addr))
#define LDG0W(dst, addr) \
    asm volatile("global_load_dword %0, %1, off sc0 sc1" \
                 : "=v"(dst) : "v"(addr))

// ---- prep kernels -------------------------------------------------------
__global__ void k_wsplit(const float* __restrict__ whh, const float* __restrict__ mask,
                         unsigned short* __restrict__ hi, unsigned short* __restrict__ lo, int n) {
    int i = blockIdx.x * blockDim.x + threadIdx.x;
    int stride = gridDim.x * blockDim.x;
    for (; i < n; i += stride) {
        float w = whh[i] * mask[i];
        unsigned short h = f2bf(w);
        hi[i] = h;
        lo[i] = f2bf(w - bf2f(h));
    }
}
__global__ void k_split(const float* __restrict__ src,
                        unsigned short* __restrict__ hi, unsigned short* __restrict__ lo, int n) {
    int i = blockIdx.x * blockDim.x + threadIdx.x;
    int stride = gridDim.x * blockDim.x;
    for (; i < n; i += stride) {
        float w = src[i];
        unsigned short h = f2bf(w);
        hi[i] = h;
        lo[i] = f2bf(w - bf2f(h));
    }
}
__global__ void k_cast(const float* __restrict__ src, unsigned short* __restrict__ dst, int n) {
    int i = blockIdx.x * blockDim.x + threadIdx.x;
    int stride = gridDim.x * blockDim.x;
    for (; i < n; i += stride) dst[i] = f2bf(src[i]);
}
// fill hs slabs 1..512 with sentinel (sc1 write-through: no dirty copies)
__global__ void k_sent(uintx4* __restrict__ p, int n4) {
    int i = blockIdx.x * blockDim.x + threadIdx.x;
    int stride = gridDim.x * blockDim.x;
    uintx4 s = {SENTW, SENTW, SENTW, SENTW};
    for (; i < n4; i += stride)
        asm volatile("global_store_dwordx4 %0, %1, off sc1"
                     :: "v"(p + i), "v"(s) : "memory");
}

// ---- persistent recurrence kernel --------------------------------------
// Round-17: SENTINEL DATAFLOW + PROBE-POLL BETWEEN SWEEPS + BURNS.
//  r16 residual analysis: step ~4.75kcy = compute ~0.9kcy + 3-4 full
//  retry sweeps (re-issue 32 b128 + RT + 16-chunk OR-validate ~1.1kcy
//  each). Detection QUANTIZATION is the cost. Changes:
//   (a) when chunks are missing after a sweep, poll a 1-dword-per-lane
//       probe (lane l -> producer l&31 of this wave's K-range; row/col
//       spread by wgl) in a tight burn loop; re-issue ONLY the missing
//       chunks when probes show data. Probe is a hint; the b128 validate
//       stays authoritative (loop repeats on partial arrival).
//   (b) burns sized up (96 initial / 24 per probe / 16 per sweep), each
//       placed before its s_waitcnt so it overlaps the RT -> VALUBusy up,
//       SCLK off the floor.
__global__ __attribute__((amdgpu_flat_work_group_size(NTHREADS, NTHREADS),
                          amdgpu_waves_per_eu(1, 1))) void k_rnn(
    const unsigned short* __restrict__ whi, const unsigned short* __restrict__ wlo,
    const unsigned short* __restrict__ wihh, const unsigned short* __restrict__ wihl,
    const unsigned short* __restrict__ xbf, const float* __restrict__ bih,
    unsigned short* hs)
{
    __shared__ float sRed[2][4 * 32 * RSTR];
    __shared__ float sBih[COLS];

    const int tid   = threadIdx.x;
    const int wg    = blockIdx.x;
    const int half  = wg >> 7;          // 0: rows 0-31, 1: rows 32-63
    const int wgl   = wg & 127;
    const int j0    = wgl * COLS;
    const int rbase = half * 32;
    const int w     = tid >> 6;
    const int lane  = tid & 63;
    const int q     = lane >> 4;
    const int nn    = lane & 15;
    const int kb    = w * 512;   // this wave's k range in H
    const int xkb   = w * 32;    // this wave's k range in I

    if (tid < COLS) sBih[tid] = bih[j0 + tid];

    // probe geometry: lane l watches producer p=l&31 (owns cols kb+p*16..
    // +15 of this wave's K-range); chunk ks=(l&31)>>1. Row spread wgl&31,
    // col spread (wgl>>4)*2 dwords -> <=1 poller per dword per half.
    const int myks = (lane & 31) >> 1;
    const size_t probe_off =
        (size_t)(rbase + (wgl & 31)) * H_ +
        (size_t)(kb + (lane & 31) * 16 + ((wgl >> 4) & 7) * 2);

    // W fragments — loaded once, laundered opaque (stay resident)
    uintx4 wh[16], wl[16], bxh_u, bxl_u;
    {
        const size_t wrow = (size_t)(j0 + nn) * H_ + (size_t)(kb + q * 8);
#pragma unroll
        for (int ks = 0; ks < 16; ++ks) {
            wh[ks] = *(const uintx4*)&whi[wrow + ks * 32];
            wl[ks] = *(const uintx4*)&wlo[wrow + ks * 32];
        }
        const size_t xrow = (size_t)(j0 + nn) * I_ + (size_t)(xkb + q * 8);
        bxh_u = *(const uintx4*)&wihh[xrow];
        bxl_u = *(const uintx4*)&wihl[xrow];
#pragma unroll
        for (int ks = 0; ks < 16; ++ks)
            asm volatile("" : "+v"(wh[ks]), "+v"(wl[ks]));
        asm volatile("" : "+v"(bxh_u), "+v"(bxl_u));
    }
    const bf16x8 bxh = __builtin_bit_cast(bf16x8, bxh_u);
    const bf16x8 bxl = __builtin_bit_cast(bf16x8, bxl_u);

    // x rows for this WG's two row-tiles
    const unsigned short* const xr0 = xbf + (size_t)(rbase + nn)      * (S_ * I_);
    const unsigned short* const xr1 = xbf + (size_t)(rbase + 16 + nn) * (S_ * I_);

    // prologue: prefetch x operands for t=0
    uintx4 xc0, xc1;
    {
        const size_t xo = (size_t)xkb + q * 8;
        xc0 = *(const uintx4*)&xr0[xo];
        xc1 = *(const uintx4*)&xr1[xo];
        asm volatile("" : "+v"(xc0), "+v"(xc1));
    }

#pragma unroll 1
    for (int t = 0; t < S_; ++t) {
        const unsigned short* hp = hs + (size_t)t * SLAB;
        const unsigned short* r0p = hp + (size_t)(rbase + nn)      * H_ + kb + q * 8;
        const unsigned short* r1p = hp + (size_t)(rbase + 16 + nn) * H_ + kb + q * 8;
        const unsigned short* ppa = hp + probe_off;

        // (1) issue ALL 32 h-loads immediately (they are also the probe)
        uintx4 g0[16], g1[16];
#pragma unroll
        for (int ks = 0; ks < 16; ++ks) {
            LDG0(g0[ks], r0p + ks * 32);
            LDG0(g1[ks], r1p + ks * 32);
        }

        // (2) register-only x-projection — overlaps the load RT
        floatx4 a0 = {0.f, 0.f, 0.f, 0.f}, a1 = a0;
        {
            bf16x8 x0 = __builtin_bit_cast(bf16x8, xc0);
            bf16x8 x1 = __builtin_bit_cast(bf16x8, xc1);
            a0 = __builtin_amdgcn_mfma_f32_16x16x32_bf16(x0, bxh, a0, 0, 0, 0);
            a1 = __builtin_amdgcn_mfma_f32_16x16x32_bf16(x1, bxh, a1, 0, 0, 0);
            a0 = __builtin_amdgcn_mfma_f32_16x16x32_bf16(x0, bxl, a0, 0, 0, 0);
            a1 = __builtin_amdgcn_mfma_f32_16x16x32_bf16(x1, bxl, a1, 0, 0, 0);
        }

        // (3) issue next-step x loads (land at loop end)
        uintx4 xn0, xn1;
        {
            const size_t xo = (size_t)((t + 1) & (S_ - 1)) * I_ + xkb + q * 8;
            xn0 = *(const uintx4*)&xr0[xo];
            xn1 = *(const uintx4*)&xr1[xo];
        }

        // anti-DVFS: overlap the in-flight RT with VALU work
        burn(96);

        // (4) validate/consume; probe-poll + selective re-issue for rest.
        asm volatile("s_waitcnt vmcnt(0)" ::: "memory");
        unsigned rem = 0xFFFFu;
        for (;;) {
            // sweep: validate remaining chunks, MFMA the newly valid
            unsigned nv = 0;
#pragma unroll
            for (int ks = 0; ks < 16; ++ks) if (rem & (1u << ks)) {
                unsigned o = g0[ks].x | g0[ks].y | g0[ks].z | g0[ks].w
                           | g1[ks].x | g1[ks].y | g1[ks].z | g1[ks].w;
                if (__ballot((o & SENTMASK) != 0u) == 0ull) nv |= 1u << ks;
            }
            nv = __builtin_amdgcn_readfirstlane(nv);
            const unsigned rem2 = rem & ~nv;
#pragma unroll
            for (int ks = 0; ks < 16; ++ks) if (nv & (1u << ks)) {
                const bf16x8 h0  = __builtin_bit_cast(bf16x8, g0[ks]);
                const bf16x8 h1  = __builtin_bit_cast(bf16x8, g1[ks]);
                const bf16x8 whk = __builtin_bit_cast(bf16x8, wh[ks]);
                const bf16x8 wlk = __builtin_bit_cast(bf16x8, wl[ks]);
                a0 = __builtin_amdgcn_mfma_f32_16x16x32_bf16(h0, whk, a0, 0, 0, 0);
                a1 = __builtin_amdgcn_mfma_f32_16x16x32_bf16(h1, whk, a1, 0, 0, 0);
                a0 = __builtin_amdgcn_mfma_f32_16x16x32_bf16(h0, wlk, a0, 0, 0, 0);
                a1 = __builtin_amdgcn_mfma_f32_16x16x32_bf16(h1, wlk, a1, 0, 0, 0);
            }
            if (!rem2) break;
            rem = rem2;

            // cheap probe-poll: 1 b32/lane until missing producers arrive
            for (;;) {
                unsigned v;
                LDG0W(v, ppa);
                burn(24);                       // overlaps probe RT
                asm volatile("s_waitcnt vmcnt(0)" ::: "memory");
                const bool bad = ((v & SENTMASK) != 0u) &&
                                 ((rem >> myks) & 1u);
                if (__ballot(bad) == 0ull) break;
            }
            // re-issue ONLY missing chunks; their RT overlaps nothing
            // heavy, so keep a small burn before the drain
#pragma unroll
            for (int ks = 0; ks < 16; ++ks) if (rem & (1u << ks)) {
                LDG0(g0[ks], r0p + ks * 32);
                LDG0(g1[ks], r1p + ks * 32);
            }
            burn(16);
            asm volatile("s_waitcnt vmcnt(0)" ::: "memory");
        }

        // (5) wave partials -> LDS (buffer t&1)
        float* sr = sRed[t & 1];
#pragma unroll
        for (int r = 0; r < 4; ++r) {
            sr[(w * 32 +      q * 4 + r) * RSTR + nn] = a0[r];
            sr[(w * 32 + 16 + q * 4 + r) * RSTR + nn] = a1[r];
        }
        __syncthreads();   // sRed ready (also isolates t vs t+2 buffer reuse)

        // (6) reduce 4 waves, +bih, tanh, pack, sc1 store. No drain, no
        //     flag, no second barrier — consumers validate the data.
        {
            const int m  = tid >> 3;          // 0..31 (row within half)
            const int n0 = (tid & 7) * 2;     // 0..14 (col pair)
            floatx2 s = *(const floatx2*)&sr[(0 * 32 + m) * RSTR + n0];
            s += *(const floatx2*)&sr[(1 * 32 + m) * RSTR + n0];
            s += *(const floatx2*)&sr[(2 * 32 + m) * RSTR + n0];
            s += *(const floatx2*)&sr[(3 * 32 + m) * RSTR + n0];
            unsigned short u0 = f2bf(fast_tanh(s[0] + sBih[n0 + 0]));
            unsigned short u1 = f2bf(fast_tanh(s[1] + sBih[n0 + 1]));
            unsigned pk = (unsigned)u0 | ((unsigned)u1 << 16);
            unsigned short* dst =
                &hs[(size_t)(t + 1) * SLAB + (size_t)(rbase + m) * H_ + j0 + n0];
            asm volatile("global_store_dword %0, %1, off sc1"
                         :: "v"(dst), "v"(pk) : "memory");
        }

        asm volatile("" : "+v"(xn0), "+v"(xn1));   // land x prefetch here
        xc0 = xn0; xc1 = xn1;
    }
}

// ---- output projection: out[b,t,o] = hs[t+1][b,:] . Who[o,:] + bho ------
__global__ __launch_bounds__(NTHREADS) void k_out(
    const unsigned short* __restrict__ hflat, const unsigned short* __restrict__ who,
    const float* __restrict__ bho, float* __restrict__ out)
{
    const int tid = threadIdx.x;
    const int w = tid >> 6, lane = tid & 63, q = lane >> 4, nn = lane & 15;
    const size_t r0 = ((size_t)blockIdx.x * 4 + w) * 16;   // row = t*64+b
    floatx4 acc[8];
#pragma unroll
    for (int i = 0; i < 8; ++i) acc[i] = floatx4{0.f, 0.f, 0.f, 0.f};
    for (int ks = 0; ks < 64; ++ks) {
        const int kk = ks * 32 + q * 8;
        bf16x8 a = *(const bf16x8*)&hflat[(r0 + nn) * H_ + kk];
#pragma unroll
        for (int nt = 0; nt < 8; ++nt) {
            bf16x8 b = *(const bf16x8*)&who[(size_t)(nt * 16 + nn) * H_ + kk];
            acc[nt] = __builtin_amdgcn_mfma_f32_16x16x32_bf16(a, b, acc[nt], 0, 0, 0);
        }
    }
#pragma unroll
    for (int nt = 0; nt < 8; ++nt) {
#pragma unroll
        for (int r = 0; r < 4; ++r) {
            size_t rr = r0 + q * 4 + r;
            int t = (int)(rr >> 6), b = (int)(rr & 63);
            int o = nt * 16 + nn;
            out[(size_t)b * (S_ * O_) + (size_t)t * O_ + o] = acc[nt][r] + bho[o];
        }
    }
}

// ---- host ----------------------------------------------------------------
extern "C" void kernel_launch(void* const* d_in, const int* in_sizes, int n_in,
                              void* d_out, int out_size, void* d_ws, size_t ws_size,
                              hipStream_t stream) {
    const float* x    = (const float*)d_in[0];
    const float* Wih  = (const float*)d_in[1];
    const float* bih  = (const float*)d_in[2];
    const float* Whh  = (const float*)d_in[3];
    const float* Who  = (const float*)d_in[4];
    const float* bho  = (const float*)d_in[5];
    const float* mask = (const float*)d_in[6];
    float* out = (float*)d_out;

    char* ws = (char*)d_ws;
    constexpr size_t HS_OFF   = 0;
    constexpr size_t HS_BYTES = (size_t)(S_ + 1) * SLAB * 2;
    constexpr size_t WHI_OFF  = HS_OFF + HS_BYTES;
    constexpr size_t WLO_OFF  = WHI_OFF + (size_t)H_ * H_ * 2;
    constexpr size_t XBF_OFF  = WLO_OFF + (size_t)H_ * H_ * 2;
    constexpr size_t WIHH_OFF = XBF_OFF + (size_t)B_ * S_ * I_ * 2;
    constexpr size_t WIHL_OFF = WIHH_OFF + (size_t)H_ * I_ * 2;
    constexpr size_t WHO_OFF  = WIHL_OFF + (size_t)H_ * I_ * 2;
    constexpr size_t WS_NEED  = WHO_OFF + (size_t)O_ * H_ * 2;
    if (ws_size < WS_NEED) return;

    unsigned short* hs    = (unsigned short*)(ws + HS_OFF);
    unsigned short* whi   = (unsigned short*)(ws + WHI_OFF);
    unsigned short* wlo   = (unsigned short*)(ws + WLO_OFF);
    unsigned short* xbf   = (unsigned short*)(ws + XBF_OFF);
    unsigned short* wihh  = (unsigned short*)(ws + WIHH_OFF);
    unsigned short* wihl  = (unsigned short*)(ws + WIHL_OFF);
    unsigned short* whobf = (unsigned short*)(ws + WHO_OFF);

    hipMemsetAsync(hs, 0, (size_t)SLAB * 2, stream);      // h(0) = 0
    // slabs 1..512 := sentinel (bit14 set) — data-arrival detector
    k_sent<<<2048, 256, 0, stream>>>((uintx4*)(hs + SLAB),
                                     (int)((size_t)S_ * SLAB / 8));

    k_wsplit<<<1024, 256, 0, stream>>>(Whh, mask, whi, wlo, H_ * H_);
    k_split <<<256, 256, 0, stream>>>(Wih, wihh, wihl, H_ * I_);
    k_cast  <<<256, 256, 0, stream>>>(Who, whobf, O_ * H_);
    k_cast  <<<1024, 256, 0, stream>>>(x, xbf, B_ * S_ * I_);

    k_rnn<<<NWG, NTHREADS, 0, stream>>>(whi, wlo, wihh, wihl, xbf, bih, hs);
    k_out<<<512, NTHREADS, 0, stream>>>(hs + SLAB, whobf, bho, out);
}

// Round 8
// 2254.164 us; speedup vs baseline: 1.6787x; 1.6787x over previous
//
#include <hip/hip_runtime.h>
#include <stdint.h>
#include <math.h>

#define B_ 64
#define S_ 512
#define I_ 128
#define H_ 2048
#define O_ 128
#define NWG 256            /* B-split: 2 independent 32-row RNN chains */
#define COLS 16
#define NTHREADS 256
#define SLAB (B_ * H_)      /* 131072 elements per h snapshot */
#define HALF_ 65536         /* elements per half-slab */
#define RSTR 20             /* sRed row stride in floats */
#define SENTW 0x7FC07FC0u   /* qNaN|qNaN — tanh output always has bit14=0 */
#define SENTMASK 0x40004000u

typedef __attribute__((ext_vector_type(8))) __bf16 bf16x8;
typedef __attribute__((ext_vector_type(4))) float floatx4;
typedef __attribute__((ext_vector_type(2))) float floatx2;
typedef __attribute__((ext_vector_type(4))) unsigned int uintx4;

__device__ __forceinline__ unsigned short f2bf(float f) {
    unsigned u = __float_as_uint(f);
    unsigned r = u + 0x7fffu + ((u >> 16) & 1u);   // RNE
    return (unsigned short)(r >> 16);
}
__device__ __forceinline__ float bf2f(unsigned short h) {
    return __uint_as_float(((unsigned)h) << 16);
}
// tanh(x) = 1 - 2/(e^{2x}+1); err ~1e-6 << bf16 noise.
__device__ __forceinline__ float fast_tanh(float x) {
    float e = __expf(2.0f * x);
    return 1.0f - 2.0f * __builtin_amdgcn_rcpf(e + 1.0f);
}

// VALU work overlapping in-flight VMEM (r16: real cycle reduction).
__device__ __forceinline__ void burn(int n) {
    float a = 1.0f, b = 1.0f;
    const float c = 1.0000001f, d = 0.9999999f;
    for (int i = 0; i < n; ++i)
        asm volatile("v_fmac_f32 %0, %2, %2\n\tv_fmac_f32 %1, %3, %3"
                     : "+v"(a), "+v"(b) : "v"(c), "v"(d));
}

// sc0 sc1 b128 load (bypass L1/L2 -> MALL truth; retry-safe)
#define LDG0(dst, addr) \
    asm volatile("global_load_dwordx4 %0, %1, off sc0 sc1" \
                 : "=v"(dst) : "v"(addr))

// ---- prep kernels -------------------------------------------------------
__global__ void k_wsplit(const float* __restrict__ whh, const float* __restrict__ mask,
                         unsigned short* __restrict__ hi, unsigned short* __restrict__ lo, int n) {
    int i = blockIdx.x * blockDim.x + threadIdx.x;
    int stride = gridDim.x * blockDim.x;
    for (; i < n; i += stride) {
        float w = whh[i] * mask[i];
        unsigned short h = f2bf(w);
        hi[i] = h;
        lo[i] = f2bf(w - bf2f(h));
    }
}
__global__ void k_split(const float* __restrict__ src,
                        unsigned short* __restrict__ hi, unsigned short* __restrict__ lo, int n) {
    int i = blockIdx.x * blockDim.x + threadIdx.x;
    int stride = gridDim.x * blockDim.x;
    for (; i < n; i += stride) {
        float w = src[i];
        unsigned short h = f2bf(w);
        hi[i] = h;
        lo[i] = f2bf(w - bf2f(h));
    }
}
__global__ void k_cast(const float* __restrict__ src, unsigned short* __restrict__ dst, int n) {
    int i = blockIdx.x * blockDim.x + threadIdx.x;
    int stride = gridDim.x * blockDim.x;
    for (; i < n; i += stride) dst[i] = f2bf(src[i]);
}
// fill hs slabs 1..512 with sentinel (sc1 write-through: no dirty copies)
__global__ void k_sent(uintx4* __restrict__ p, int n4) {
    int i = blockIdx.x * blockDim.x + threadIdx.x;
    int stride = gridDim.x * blockDim.x;
    uintx4 s = {SENTW, SENTW, SENTW, SENTW};
    for (; i < n4; i += stride)
        asm volatile("global_store_dwordx4 %0, %1, off sc1"
                     :: "v"(p + i), "v"(s) : "memory");
}

// ---- persistent recurrence kernel --------------------------------------
// Round-18: COALESCED PUBLISH LAYOUT (r16 protocol unchanged).
//  Model correction: MfmaUtil is chip-normalized; cross-checking r0/r13/
//  r16 gives clock = 2.4 GHz throughout (DVFS theory dead). Step is
//  ~16kcy, compute ~2kcy. The component every protocol shares: h loads
//  were 16-way line scatter per b128 (64 lanes on 4KB-apart rows),
//  uncached, ~13 sweeps/step; producer stores equally scattered.
//  New slab layout (per half): element (row=rb*16+nn, col=w*512+ks*32+
//  q*8+j)  ->  half*65536 + (w*16+ks)*1024 + rb*512 + (q*16+nn)*8 + j.
//  Consumer chunk = TWO contiguous 1KB blocks, addr = base + lane*16B
//  (lane order == address order, perfectly coalesced). Producer epilogue
//  fills dense 512B spans. k_out reads the same layout (also coalesced).
__global__ __attribute__((amdgpu_flat_work_group_size(NTHREADS, NTHREADS),
                          amdgpu_waves_per_eu(1, 1))) void k_rnn(
    const unsigned short* __restrict__ whi, const unsigned short* __restrict__ wlo,
    const unsigned short* __restrict__ wihh, const unsigned short* __restrict__ wihl,
    const unsigned short* __restrict__ xbf, const float* __restrict__ bih,
    unsigned short* hs)
{
    __shared__ float sRed[2][4 * 32 * RSTR];
    __shared__ float sBih[COLS];

    const int tid   = threadIdx.x;
    const int wg    = blockIdx.x;
    const int half  = wg >> 7;          // 0: rows 0-31, 1: rows 32-63
    const int wgl   = wg & 127;
    const int j0    = wgl * COLS;
    const int rbase = half * 32;
    const int w     = tid >> 6;
    const int lane  = tid & 63;
    const int q     = lane >> 4;
    const int nn    = lane & 15;
    const int kb    = w * 512;   // this wave's k range in H
    const int xkb   = w * 32;    // this wave's k range in I

    if (tid < COLS) sBih[tid] = bih[j0 + tid];

    // W fragments — loaded once, laundered opaque (stay resident)
    uintx4 wh[16], wl[16], bxh_u, bxl_u;
    {
        const size_t wrow = (size_t)(j0 + nn) * H_ + (size_t)(kb + q * 8);
#pragma unroll
        for (int ks = 0; ks < 16; ++ks) {
            wh[ks] = *(const uintx4*)&whi[wrow + ks * 32];
            wl[ks] = *(const uintx4*)&wlo[wrow + ks * 32];
        }
        const size_t xrow = (size_t)(j0 + nn) * I_ + (size_t)(xkb + q * 8);
        bxh_u = *(const uintx4*)&wihh[xrow];
        bxl_u = *(const uintx4*)&wihl[xrow];
#pragma unroll
        for (int ks = 0; ks < 16; ++ks)
            asm volatile("" : "+v"(wh[ks]), "+v"(wl[ks]));
        asm volatile("" : "+v"(bxh_u), "+v"(bxl_u));
    }
    const bf16x8 bxh = __builtin_bit_cast(bf16x8, bxh_u);
    const bf16x8 bxl = __builtin_bit_cast(bf16x8, bxl_u);

    // consumer base: this wave's 16 blocks start at half*65536 + w*16384;
    // per-lane segment offset = lane*8 elements (16B). Fresh +t*SLAB per t.
    const unsigned short* const cwbase =
        hs + (size_t)half * HALF_ + (size_t)w * 16384 + (size_t)lane * 8;

    // producer publish offset for this thread (2 elements per step):
    //  m = row within half, n0 = col pair within our 16-col tile
    const int m  = tid >> 3;
    const int n0 = (tid & 7) * 2;
    const size_t pub_off =
        (size_t)half * HALF_ +
        (size_t)((wgl >> 5) * 16 + ((wgl >> 1) & 15)) * 1024 +
        (size_t)(m >> 4) * 512 +
        (size_t)(((wgl & 1) * 2 + (n0 >> 3)) * 16 + (m & 15)) * 8 +
        (size_t)(n0 & 7);

    // x rows for this WG's two row-tiles
    const unsigned short* const xr0 = xbf + (size_t)(rbase + nn)      * (S_ * I_);
    const unsigned short* const xr1 = xbf + (size_t)(rbase + 16 + nn) * (S_ * I_);

    // prologue: prefetch x operands for t=0
    uintx4 xc0, xc1;
    {
        const size_t xo = (size_t)xkb + q * 8;
        xc0 = *(const uintx4*)&xr0[xo];
        xc1 = *(const uintx4*)&xr1[xo];
        asm volatile("" : "+v"(xc0), "+v"(xc1));
    }

#pragma unroll 1
    for (int t = 0; t < S_; ++t) {
        const unsigned short* cb = cwbase + (size_t)t * SLAB;

        // (1) issue ALL 32 h-loads immediately (they are also the probe)
        uintx4 g0[16], g1[16];
#pragma unroll
        for (int ks = 0; ks < 16; ++ks) {
            LDG0(g0[ks], cb + ks * 1024);        // rb0 block (rows 0-15)
            LDG0(g1[ks], cb + ks * 1024 + 512);  // rb1 block (rows 16-31)
        }

        // (2) register-only x-projection — overlaps the load RT
        floatx4 a0 = {0.f, 0.f, 0.f, 0.f}, a1 = a0;
        {
            bf16x8 x0 = __builtin_bit_cast(bf16x8, xc0);
            bf16x8 x1 = __builtin_bit_cast(bf16x8, xc1);
            a0 = __builtin_amdgcn_mfma_f32_16x16x32_bf16(x0, bxh, a0, 0, 0, 0);
            a1 = __builtin_amdgcn_mfma_f32_16x16x32_bf16(x1, bxh, a1, 0, 0, 0);
            a0 = __builtin_amdgcn_mfma_f32_16x16x32_bf16(x0, bxl, a0, 0, 0, 0);
            a1 = __builtin_amdgcn_mfma_f32_16x16x32_bf16(x1, bxl, a1, 0, 0, 0);
        }

        // (3) issue next-step x loads (land at loop end)
        uintx4 xn0, xn1;
        {
            const size_t xo = (size_t)((t + 1) & (S_ - 1)) * I_ + xkb + q * 8;
            xn0 = *(const uintx4*)&xr0[xo];
            xn1 = *(const uintx4*)&xr1[xo];
        }

        // anti-stall: overlap the in-flight RT with VALU work
        burn(96);

        // (4) validate per chunk; MFMA valid chunks; selective retry.
        asm volatile("s_waitcnt vmcnt(0)" ::: "memory");
        unsigned rem = 0xFFFFu;
        for (;;) {
            unsigned nv = 0;
#pragma unroll
            for (int ks = 0; ks < 16; ++ks) if (rem & (1u << ks)) {
                unsigned o = g0[ks].x | g0[ks].y | g0[ks].z | g0[ks].w
                           | g1[ks].x | g1[ks].y | g1[ks].z | g1[ks].w;
                if (__ballot((o & SENTMASK) != 0u) == 0ull) nv |= 1u << ks;
            }
            nv = __builtin_amdgcn_readfirstlane(nv);
            const unsigned rem2 = rem & ~nv;
            // re-issue stragglers FIRST (their RT overlaps the work below)
            if (rem2) {
#pragma unroll
                for (int ks = 0; ks < 16; ++ks) if (rem2 & (1u << ks)) {
                    LDG0(g0[ks], cb + ks * 1024);
                    LDG0(g1[ks], cb + ks * 1024 + 512);
                }
            }
            // consume newly-valid chunks (accumulation order irrelevant)
#pragma unroll
            for (int ks = 0; ks < 16; ++ks) if (nv & (1u << ks)) {
                const bf16x8 h0  = __builtin_bit_cast(bf16x8, g0[ks]);
                const bf16x8 h1  = __builtin_bit_cast(bf16x8, g1[ks]);
                const bf16x8 whk = __builtin_bit_cast(bf16x8, wh[ks]);
                const bf16x8 wlk = __builtin_bit_cast(bf16x8, wl[ks]);
                a0 = __builtin_amdgcn_mfma_f32_16x16x32_bf16(h0, whk, a0, 0, 0, 0);
                a1 = __builtin_amdgcn_mfma_f32_16x16x32_bf16(h1, whk, a1, 0, 0, 0);
                a0 = __builtin_amdgcn_mfma_f32_16x16x32_bf16(h0, wlk, a0, 0, 0, 0);
                a1 = __builtin_amdgcn_mfma_f32_16x16x32_bf16(h1, wlk, a1, 0, 0, 0);
            }
            if (!rem2) break;
            if (nv == 0) burn(96);   // stall path: stay busy, overlap RT
            rem = rem2;
            asm volatile("s_waitcnt vmcnt(0)" ::: "memory");
        }

        // (5) wave partials -> LDS (buffer t&1)
        float* sr = sRed[t & 1];
#pragma unroll
        for (int r = 0; r < 4; ++r) {
            sr[(w * 32 +      q * 4 + r) * RSTR + nn] = a0[r];
            sr[(w * 32 + 16 + q * 4 + r) * RSTR + nn] = a1[r];
        }
        __syncthreads();   // sRed ready (also isolates t vs t+2 buffer reuse)

        // (6) reduce 4 waves, +bih, tanh, pack, sc1 store into PUBLISH
        //     layout. No drain, no flag — consumers validate the data.
        {
            floatx2 s = *(const floatx2*)&sr[(0 * 32 + m) * RSTR + n0];
            s += *(const floatx2*)&sr[(1 * 32 + m) * RSTR + n0];
            s += *(const floatx2*)&sr[(2 * 32 + m) * RSTR + n0];
            s += *(const floatx2*)&sr[(3 * 32 + m) * RSTR + n0];
            unsigned short u0 = f2bf(fast_tanh(s[0] + sBih[n0 + 0]));
            unsigned short u1 = f2bf(fast_tanh(s[1] + sBih[n0 + 1]));
            unsigned pk = (unsigned)u0 | ((unsigned)u1 << 16);
            unsigned short* dst = hs + (size_t)(t + 1) * SLAB + pub_off;
            asm volatile("global_store_dword %0, %1, off sc1"
                         :: "v"(dst), "v"(pk) : "memory");
        }

        asm volatile("" : "+v"(xn0), "+v"(xn1));   // land x prefetch here
        xc0 = xn0; xc1 = xn1;
    }
}

// ---- output projection: out[b,t,o] = hs[t+1][b,:] . Who[o,:] + bho ------
// hflat points at slab 1; slabs are in PUBLISH layout (see k_rnn header).
__global__ __launch_bounds__(NTHREADS) void k_out(
    const unsigned short* __restrict__ hflat, const unsigned short* __restrict__ who,
    const float* __restrict__ bho, float* __restrict__ out)
{
    const int tid = threadIdx.x;
    const int w = tid >> 6, lane = tid & 63, q = lane >> 4, nn = lane & 15;
    const int r0 = ((int)blockIdx.x * 4 + w) * 16;   // flat row = t*64+b
    const int t    = r0 >> 6;
    const int half = (r0 >> 5) & 1;
    const int rb   = (r0 >> 4) & 1;
    // A base in publish layout: lane-ordered 16B segments, +ks*1024/iter
    const unsigned short* const abase =
        hflat + (size_t)t * SLAB + (size_t)half * HALF_ +
        (size_t)rb * 512 + (size_t)lane * 8;
    floatx4 acc[8];
#pragma unroll
    for (int i = 0; i < 8; ++i) acc[i] = floatx4{0.f, 0.f, 0.f, 0.f};
    for (int ks = 0; ks < 64; ++ks) {
        const int kk = ks * 32 + q * 8;
        bf16x8 a = *(const bf16x8*)(abase + ks * 1024);
#pragma unroll
        for (int nt = 0; nt < 8; ++nt) {
            bf16x8 b = *(const bf16x8*)&who[(size_t)(nt * 16 + nn) * H_ + kk];
            acc[nt] = __builtin_amdgcn_mfma_f32_16x16x32_bf16(a, b, acc[nt], 0, 0, 0);
        }
    }
#pragma unroll
    for (int nt = 0; nt < 8; ++nt) {
#pragma unroll
        for (int r = 0; r < 4; ++r) {
            int rr = r0 + q * 4 + r;
            int tt = rr >> 6, b = rr & 63;
            int o = nt * 16 + nn;
            out[(size_t)b * (S_ * O_) + (size_t)tt * O_ + o] = acc[nt][r] + bho[o];
        }
    }
}

// ---- host ----------------------------------------------------------------
extern "C" void kernel_launch(void* const* d_in, const int* in_sizes, int n_in,
                              void* d_out, int out_size, void* d_ws, size_t ws_size,
                              hipStream_t stream) {
    const float* x    = (const float*)d_in[0];
    const float* Wih  = (const float*)d_in[1];
    const float* bih  = (const float*)d_in[2];
    const float* Whh  = (const float*)d_in[3];
    const float* Who  = (const float*)d_in[4];
    const float* bho  = (const float*)d_in[5];
    const float* mask = (const float*)d_in[6];
    float* out = (float*)d_out;

    char* ws = (char*)d_ws;
    constexpr size_t HS_OFF   = 0;
    constexpr size_t HS_BYTES = (size_t)(S_ + 1) * SLAB * 2;
    constexpr size_t WHI_OFF  = HS_OFF + HS_BYTES;
    constexpr size_t WLO_OFF  = WHI_OFF + (size_t)H_ * H_ * 2;
    constexpr size_t XBF_OFF  = WLO_OFF + (size_t)H_ * H_ * 2;
    constexpr size_t WIHH_OFF = XBF_OFF + (size_t)B_ * S_ * I_ * 2;
    constexpr size_t WIHL_OFF = WIHH_OFF + (size_t)H_ * I_ * 2;
    constexpr size_t WHO_OFF  = WIHL_OFF + (size_t)H_ * I_ * 2;
    constexpr size_t WS_NEED  = WHO_OFF + (size_t)O_ * H_ * 2;
    if (ws_size < WS_NEED) return;

    unsigned short* hs    = (unsigned short*)(ws + HS_OFF);
    unsigned short* whi   = (unsigned short*)(ws + WHI_OFF);
    unsigned short* wlo   = (unsigned short*)(ws + WLO_OFF);
    unsigned short* xbf   = (unsigned short*)(ws + XBF_OFF);
    unsigned short* wihh  = (unsigned short*)(ws + WIHH_OFF);
    unsigned short* wihl  = (unsigned short*)(ws + WIHL_OFF);
    unsigned short* whobf = (unsigned short*)(ws + WHO_OFF);

    hipMemsetAsync(hs, 0, (size_t)SLAB * 2, stream);      // h(0) = 0 (any layout)
    // slabs 1..512 := sentinel (bit14 set) — data-arrival detector
    k_sent<<<2048, 256, 0, stream>>>((uintx4*)(hs + SLAB),
                                     (int)((size_t)S_ * SLAB / 8));

    k_wsplit<<<1024, 256, 0, stream>>>(Whh, mask, whi, wlo, H_ * H_);
    k_split <<<256, 256, 0, stream>>>(Wih, wihh, wihl, H_ * I_);
    k_cast  <<<256, 256, 0, stream>>>(Who, whobf, O_ * H_);
    k_cast  <<<1024, 256, 0, stream>>>(x, xbf, B_ * S_ * I_);

    k_rnn<<<NWG, NTHREADS, 0, stream>>>(whi, wlo, wihh, wihl, xbf, bih, hs);
    k_out<<<512, NTHREADS, 0, stream>>>(hs + SLAB, whobf, bho, out);
}